// Round 1
// baseline (293.069 us; speedup 1.0000x reference)
//
#include <hip/hip_runtime.h>
#include <hip/hip_bf16.h>
#include <math.h>

#define NN 8192      // nodes
#define NK 64        // clusters
#define EPSF 1e-6f

typedef __attribute__((ext_vector_type(8))) short s16x8;
typedef __attribute__((ext_vector_type(4))) short s16x4;
typedef __attribute__((ext_vector_type(4))) float f32x4;

static __device__ __forceinline__ short f2bf(float x) {
    union { float f; unsigned u; } v; v.f = x;
    unsigned r = (v.u + 0x7fffu + ((v.u >> 16) & 1u)) >> 16;
    return (short)r;
}

// ---------- pre-kernel: A [N][64] f32 -> AT [64][N] bf16 ----------
__global__ __launch_bounds__(256) void cvt_at(const float* __restrict__ A,
                                              unsigned short* __restrict__ AT) {
    int gid = blockIdx.x * 256 + threadIdx.x;   // N*16 total
    int i = gid >> 4;
    int k4 = (gid & 15) << 2;
    f32x4 v = *(const f32x4*)(A + (size_t)i * NK + k4);
    size_t base = (size_t)k4 * NN + i;
    AT[base]            = (unsigned short)f2bf(v[0]);
    AT[base + NN]       = (unsigned short)f2bf(v[1]);
    AT[base + 2 * (size_t)NN] = (unsigned short)f2bf(v[2]);
    AT[base + 3 * (size_t)NN] = (unsigned short)f2bf(v[3]);
}

// ---------- main fused pass over E ----------
// grid = 128 i-tiles * 8 j-splits = 1024 blocks, 256 threads (4 waves)
__global__ __launch_bounds__(256) void pass_e(
    const float* __restrict__ E, const float* __restrict__ A,
    const unsigned short* __restrict__ AT,
    float* __restrict__ rowsum, float* __restrict__ colsum,
    float* __restrict__ within)
{
    __shared__ short Elds[64][40];   // 64 rows x 32 j-cols, stride 40 bf16 (80B)
    __shared__ short Alds[64][40];   // 64 k-rows x 32 j-cols
    __shared__ float csum[1024];
    __shared__ float red[4];

    const int N = NN;
    int tid = threadIdx.x;
    int bid = blockIdx.x;
    int itile = bid >> 3;
    int js = bid & 7;
    int i0 = itile * 64;
    const int jrange = 1024;
    int j0 = js * jrange;

    for (int c = tid; c < jrange; c += 256) csum[c] = 0.f;

    int w = tid >> 6;            // wave id -> i-subtile
    int l = tid & 63;
    int lmod = l & 15, ldiv = l >> 4;

    int srow = tid >> 3;         // 0..31 (E staging row, pass adds +32)
    int scol = (tid & 7) << 2;   // 0,4,...,28
    int arow = tid >> 2;         // 0..63 (AT k-row)
    int acolb = (tid & 3) << 3;  // 0,8,16,24 (j offset)

    f32x4 D0 = {0.f,0.f,0.f,0.f}, D1 = D0, D2 = D0, D3 = D0;
    float rs0 = 0.f, rs1 = 0.f;

    const float* e0p = E + (size_t)(i0 + srow) * N + scol;
    const float* e1p = E + (size_t)(i0 + 32 + srow) * N + scol;
    const unsigned short* ap = AT + (size_t)arow * N + acolb;

    __syncthreads();   // csum zeroed

    for (int jc = j0; jc < j0 + jrange; jc += 32) {
        f32x4 e0 = *(const f32x4*)(e0p + jc);
        f32x4 e1 = *(const f32x4*)(e1p + jc);
        s16x8 av = *(const s16x8*)(ap + jc);

        rs0 += e0[0] + e0[1] + e0[2] + e0[3];
        rs1 += e1[0] + e1[1] + e1[2] + e1[3];

        int cbase = (jc - j0) + scol;
        atomicAdd(&csum[cbase + 0], e0[0] + e1[0]);
        atomicAdd(&csum[cbase + 1], e0[1] + e1[1]);
        atomicAdd(&csum[cbase + 2], e0[2] + e1[2]);
        atomicAdd(&csum[cbase + 3], e0[3] + e1[3]);

        s16x4 b0 = { f2bf(e0[0]), f2bf(e0[1]), f2bf(e0[2]), f2bf(e0[3]) };
        s16x4 b1 = { f2bf(e1[0]), f2bf(e1[1]), f2bf(e1[2]), f2bf(e1[3]) };
        *(s16x4*)&Elds[srow][scol]      = b0;
        *(s16x4*)&Elds[srow + 32][scol] = b1;
        *(s16x8*)&Alds[arow][acolb]     = av;
        __syncthreads();

        s16x8 ef = *(const s16x8*)&Elds[w * 16 + lmod][ldiv * 8];
        D0 = __builtin_amdgcn_mfma_f32_16x16x32_bf16(ef, *(const s16x8*)&Alds[ 0 + lmod][ldiv * 8], D0, 0, 0, 0);
        D1 = __builtin_amdgcn_mfma_f32_16x16x32_bf16(ef, *(const s16x8*)&Alds[16 + lmod][ldiv * 8], D1, 0, 0, 0);
        D2 = __builtin_amdgcn_mfma_f32_16x16x32_bf16(ef, *(const s16x8*)&Alds[32 + lmod][ldiv * 8], D2, 0, 0, 0);
        D3 = __builtin_amdgcn_mfma_f32_16x16x32_bf16(ef, *(const s16x8*)&Alds[48 + lmod][ldiv * 8], D3, 0, 0, 0);
        __syncthreads();
    }

    // row sums: 8 consecutive lanes share a row
    rs0 += __shfl_down(rs0, 1); rs0 += __shfl_down(rs0, 2); rs0 += __shfl_down(rs0, 4);
    rs1 += __shfl_down(rs1, 1); rs1 += __shfl_down(rs1, 2); rs1 += __shfl_down(rs1, 4);
    if ((tid & 7) == 0) {
        atomicAdd(&rowsum[i0 + srow], rs0);
        atomicAdd(&rowsum[i0 + 32 + srow], rs1);
    }
    __syncthreads();
    for (int c = tid; c < jrange; c += 256) atomicAdd(&colsum[j0 + c], csum[c]);

    // within partial: sum_{i,k} D[i][k] * A_f32[i][k]
    float wsum = 0.f;
    const float* Abase = A + (size_t)(i0 + w * 16 + 4 * ldiv) * NK + lmod;
#pragma unroll
    for (int r = 0; r < 4; ++r) {
        const float* ar = Abase + (size_t)r * NK;
        wsum += D0[r] * ar[0];
        wsum += D1[r] * ar[16];
        wsum += D2[r] * ar[32];
        wsum += D3[r] * ar[48];
    }
#pragma unroll
    for (int m = 1; m < 64; m <<= 1) wsum += __shfl_xor(wsum, m);
    if (l == 0) red[w] = wsum;
    __syncthreads();
    if (tid == 0) atomicAdd(within, red[0] + red[1] + red[2] + red[3]);
}

// ---------- spatial pass 1: argmax ids + counts + coord sums ----------
// one wave per node, 4 nodes per block, grid = N/4
__global__ __launch_bounds__(256) void spatial1(
    const float* __restrict__ A, const float* __restrict__ pos,
    int* __restrict__ ids, float* __restrict__ counts, float* __restrict__ sums)
{
    int wv = threadIdx.x >> 6, l = threadIdx.x & 63;
    int node = blockIdx.x * 4 + wv;
    float v = A[(size_t)node * NK + l];
    int idx = l;
#pragma unroll
    for (int m = 1; m < 64; m <<= 1) {
        float ov = __shfl_xor(v, m);
        int oi = __shfl_xor(idx, m);
        if (ov > v || (ov == v && oi < idx)) { v = ov; idx = oi; }
    }
    if (l == 0) {
        ids[node] = idx;
        atomicAdd(&counts[idx], 1.0f);
        atomicAdd(&sums[idx * 2 + 0], pos[(size_t)node * 2 + 0]);
        atomicAdd(&sums[idx * 2 + 1], pos[(size_t)node * 2 + 1]);
    }
}

// ---------- spatial pass 2: distances to centroids ----------
__global__ __launch_bounds__(256) void spatial2(
    const int* __restrict__ ids, const float* __restrict__ pos,
    const float* __restrict__ counts, const float* __restrict__ sums,
    float* __restrict__ distsum, int* __restrict__ maxid)
{
    __shared__ float ds[64];
    __shared__ int mx;
    int tid = threadIdx.x;
    if (tid < 64) ds[tid] = 0.f;
    if (tid == 0) mx = 0;
    __syncthreads();
    int i = blockIdx.x * 256 + tid;
    int id = ids[i];
    float den = counts[id] + EPSF;
    float cx = sums[id * 2 + 0] / den;
    float cy = sums[id * 2 + 1] / den;
    float dx = pos[(size_t)i * 2 + 0] - cx;
    float dy = pos[(size_t)i * 2 + 1] - cy;
    atomicAdd(&ds[id], sqrtf(dx * dx + dy * dy));
    atomicMax(&mx, id);
    __syncthreads();
    if (tid < 64) atomicAdd(&distsum[tid], ds[tid]);
    if (tid == 0) atomicMax(maxid, mx);
}

// ---------- finalize ----------
__global__ __launch_bounds__(256) void finalize(
    const float* __restrict__ rowsum, const float* __restrict__ colsum,
    const float* __restrict__ cons, const float* __restrict__ gen,
    const float* __restrict__ within, const float* __restrict__ counts,
    const float* __restrict__ distsum, const int* __restrict__ maxid,
    float* __restrict__ out)
{
    __shared__ float redb[4], rede[4];
    int tid = threadIdx.x;
    int w = tid >> 6, l = tid & 63;
    float bacc = 0.f, eacc = 0.f;
    for (int i = tid; i < NN; i += 256) {
        float imb = (cons[i] - gen[i]) - (colsum[i] - rowsum[i]);
        bacc += imb * imb;
        eacc += rowsum[i];
    }
#pragma unroll
    for (int m = 1; m < 64; m <<= 1) { bacc += __shfl_xor(bacc, m); eacc += __shfl_xor(eacc, m); }
    if (l == 0) { redb[w] = bacc; rede[w] = eacc; }
    __syncthreads();

    float sacc = 0.f;
    if (tid < 64) {
        float c = counts[tid];
        float avg = distsum[tid] / (c + EPSF);
        sacc = (c >= 2.0f) ? avg : 0.f;
#pragma unroll
        for (int m = 1; m < 64; m <<= 1) sacc += __shfl_xor(sacc, m);
    }
    if (tid == 0) {
        float balance = (redb[0] + redb[1] + redb[2] + redb[3]) / (float)NN;
        float sumE = rede[0] + rede[1] + rede[2] + rede[3];
        float clustering = (sumE - 2.0f * within[0]) / ((float)NN * (float)NN + EPSF);
        float nc = (float)(maxid[0] + 1) + EPSF;
        float spatial = sacc / nc;
        float total = 1.0f * balance + 0.5f * spatial + 0.3f * clustering;
        out[0] = total;
        out[1] = balance;
        out[2] = spatial;
        out[3] = clustering;
    }
}

extern "C" void kernel_launch(void* const* d_in, const int* in_sizes, int n_in,
                              void* d_out, int out_size, void* d_ws, size_t ws_size,
                              hipStream_t stream) {
    const float* E    = (const float*)d_in[0];
    const float* A    = (const float*)d_in[1];
    const float* pos  = (const float*)d_in[2];
    const float* cons = (const float*)d_in[3];
    const float* gen  = (const float*)d_in[4];
    float* out = (float*)d_out;

    char* ws = (char*)d_ws;
    unsigned short* AT = (unsigned short*)ws;                 // 64*N bf16 = 1 MB
    float* rowsum  = (float*)(ws + (size_t)2 * NK * NN);
    float* colsum  = rowsum + NN;
    float* within  = colsum + NN;
    float* counts  = within + 1;
    float* sums    = counts + 64;      // [64][2]
    float* distsum = sums + 128;
    int*   maxid   = (int*)(distsum + 64);
    int*   ids     = maxid + 1;        // [N]

    size_t zbytes = ((size_t)NN * 2 + 1 + 64 + 128 + 64 + 1) * 4;
    hipMemsetAsync(rowsum, 0, zbytes, stream);

    cvt_at  <<<NN * 16 / 256, 256, 0, stream>>>(A, AT);
    pass_e  <<<(NN / 64) * 8, 256, 0, stream>>>(E, A, AT, rowsum, colsum, within);
    spatial1<<<NN / 4, 256, 0, stream>>>(A, pos, ids, counts, sums);
    spatial2<<<NN / 256, 256, 0, stream>>>(ids, pos, counts, sums, distsum, maxid);
    finalize<<<1, 256, 0, stream>>>(rowsum, colsum, cons, gen, within, counts, distsum, maxid, out);
}

// Round 2
// 196.431 us; speedup vs baseline: 1.4920x; 1.4920x over previous
//
#include <hip/hip_runtime.h>
#include <hip/hip_bf16.h>
#include <math.h>

#define NN 8192      // nodes
#define NK 64        // clusters
#define EPSF 1e-6f
#define JSPLIT 8
#define JRANGE 1024  // NN / JSPLIT
#define NCHUNK 32    // JRANGE / 32

typedef __attribute__((ext_vector_type(8))) short s16x8;
typedef __attribute__((ext_vector_type(4))) float f32x4;

static __device__ __forceinline__ short f2bf(float x) {
    union { float f; unsigned u; } v; v.f = x;
    unsigned r = (v.u + 0x7fffu + ((v.u >> 16) & 1u)) >> 16;
    return (short)r;
}

// ---------- pre-kernel: A [N][64] f32 -> AT [64][N] bf16 ----------
__global__ __launch_bounds__(256) void cvt_at(const float* __restrict__ A,
                                              unsigned short* __restrict__ AT) {
    int gid = blockIdx.x * 256 + threadIdx.x;   // N*16 total
    int i = gid >> 4;
    int k4 = (gid & 15) << 2;
    f32x4 v = *(const f32x4*)(A + (size_t)i * NK + k4);
    size_t base = (size_t)k4 * NN + i;
    AT[base]                  = (unsigned short)f2bf(v[0]);
    AT[base + NN]             = (unsigned short)f2bf(v[1]);
    AT[base + 2 * (size_t)NN] = (unsigned short)f2bf(v[2]);
    AT[base + 3 * (size_t)NN] = (unsigned short)f2bf(v[3]);
}

// ---------- main fused pass over E (barrier-free main loop) ----------
// grid = 128 i-tiles * 8 j-splits = 1024 blocks, 256 threads (4 waves)
// wave w owns rows i0+16w..i0+16w+15; sweeps its js j-range in 32-col chunks
// with a per-(itile,wave,js) rotated start to decorrelate HBM channels.
__global__ __launch_bounds__(256, 4) void pass_e(
    const float* __restrict__ E, const float* __restrict__ A,
    const unsigned short* __restrict__ AT,
    float* __restrict__ rowsum, float* __restrict__ colsum,
    float* __restrict__ within_part)
{
    __shared__ float csum[4][JRANGE];   // per-wave column partials
    __shared__ float red[4];

    int tid = threadIdx.x;
    int w = tid >> 6, l = tid & 63;
    int bid = blockIdx.x;
    int itile = bid >> 3;      // 0..127
    int js = bid & 7;          // 0..7
    int i0 = itile * 64;
    int j0 = js * JRANGE;

    float* cflat = &csum[0][0];
    for (int i = tid; i < 4 * JRANGE; i += 256) cflat[i] = 0.f;
    __syncthreads();

    int lm = l & 15, lg = l >> 4;
    int row = i0 + 16 * w + lm;
    const float* erow = E + (size_t)row * NN;
    const unsigned short* at0 = AT + (size_t)(lm +  0) * NN;
    const unsigned short* at1 = AT + (size_t)(lm + 16) * NN;
    const unsigned short* at2 = AT + (size_t)(lm + 32) * NN;
    const unsigned short* at3 = AT + (size_t)(lm + 48) * NN;

    int s0 = (itile * 2 + w * 5 + js * 3) & (NCHUNK - 1);  // chunk rotation

    f32x4 D0 = {0.f,0.f,0.f,0.f}, D1 = D0, D2 = D0, D3 = D0;
    float racc = 0.f;

    // prologue: chunk t=0
    int jc = j0 + s0 * 32;
    int off = jc + 8 * lg;
    f32x4 va = *(const f32x4*)(erow + off);
    f32x4 vb = *(const f32x4*)(erow + off + 4);
    s16x8 b0 = *(const s16x8*)(at0 + off);
    s16x8 b1 = *(const s16x8*)(at1 + off);
    s16x8 b2 = *(const s16x8*)(at2 + off);
    s16x8 b3 = *(const s16x8*)(at3 + off);
    int jc_cur = jc;

    for (int t = 0; t < NCHUNK; ++t) {
        // prefetch next chunk (t=NCHUNK-1 wraps: redundant but branch-free)
        int jcn = j0 + ((s0 + t + 1) & (NCHUNK - 1)) * 32;
        int offn = jcn + 8 * lg;
        f32x4 na = *(const f32x4*)(erow + offn);
        f32x4 nb = *(const f32x4*)(erow + offn + 4);
        s16x8 nb0 = *(const s16x8*)(at0 + offn);
        s16x8 nb1 = *(const s16x8*)(at1 + offn);
        s16x8 nb2 = *(const s16x8*)(at2 + offn);
        s16x8 nb3 = *(const s16x8*)(at3 + offn);

        float v0 = va[0], v1 = va[1], v2 = va[2], v3 = va[3];
        float v4 = vb[0], v5 = vb[1], v6 = vb[2], v7 = vb[3];

        // rowsum partial (f32 exact)
        racc += ((v0 + v1) + (v2 + v3)) + ((v4 + v5) + (v6 + v7));

        // colsum: reduce over the 16 row-lanes (masks 1,2,4,8), deposit by lane lm==0
        float c0=v0,c1=v1,c2=v2,c3=v3,c4=v4,c5=v5,c6=v6,c7=v7;
        c0 += __shfl_xor(c0,1); c0 += __shfl_xor(c0,2); c0 += __shfl_xor(c0,4); c0 += __shfl_xor(c0,8);
        c1 += __shfl_xor(c1,1); c1 += __shfl_xor(c1,2); c1 += __shfl_xor(c1,4); c1 += __shfl_xor(c1,8);
        c2 += __shfl_xor(c2,1); c2 += __shfl_xor(c2,2); c2 += __shfl_xor(c2,4); c2 += __shfl_xor(c2,8);
        c3 += __shfl_xor(c3,1); c3 += __shfl_xor(c3,2); c3 += __shfl_xor(c3,4); c3 += __shfl_xor(c3,8);
        c4 += __shfl_xor(c4,1); c4 += __shfl_xor(c4,2); c4 += __shfl_xor(c4,4); c4 += __shfl_xor(c4,8);
        c5 += __shfl_xor(c5,1); c5 += __shfl_xor(c5,2); c5 += __shfl_xor(c5,4); c5 += __shfl_xor(c5,8);
        c6 += __shfl_xor(c6,1); c6 += __shfl_xor(c6,2); c6 += __shfl_xor(c6,4); c6 += __shfl_xor(c6,8);
        c7 += __shfl_xor(c7,1); c7 += __shfl_xor(c7,2); c7 += __shfl_xor(c7,4); c7 += __shfl_xor(c7,8);
        if (lm == 0) {
            int base = (jc_cur - j0) + 8 * lg;   // distinct addrs per (w,lg,e): no conflict
            csum[w][base + 0] += c0; csum[w][base + 1] += c1;
            csum[w][base + 2] += c2; csum[w][base + 3] += c3;
            csum[w][base + 4] += c4; csum[w][base + 5] += c5;
            csum[w][base + 6] += c6; csum[w][base + 7] += c7;
        }

        // bf16 A-fragment + 4 MFMAs (D[i][cluster] += E*A)
        s16x8 ef;
        ef[0]=f2bf(v0); ef[1]=f2bf(v1); ef[2]=f2bf(v2); ef[3]=f2bf(v3);
        ef[4]=f2bf(v4); ef[5]=f2bf(v5); ef[6]=f2bf(v6); ef[7]=f2bf(v7);
        D0 = __builtin_amdgcn_mfma_f32_16x16x32_bf16(ef, b0, D0, 0, 0, 0);
        D1 = __builtin_amdgcn_mfma_f32_16x16x32_bf16(ef, b1, D1, 0, 0, 0);
        D2 = __builtin_amdgcn_mfma_f32_16x16x32_bf16(ef, b2, D2, 0, 0, 0);
        D3 = __builtin_amdgcn_mfma_f32_16x16x32_bf16(ef, b3, D3, 0, 0, 0);

        va = na; vb = nb; b0 = nb0; b1 = nb1; b2 = nb2; b3 = nb3;
        jc_cur = jcn;
    }

    // rowsum: sum the 4 lg-lanes sharing a row
    racc += __shfl_xor(racc, 16);
    racc += __shfl_xor(racc, 32);
    if (l < 16) atomicAdd(&rowsum[i0 + 16 * w + l], racc);

    // within partial: sum_{i,k} D[i][k] * A_f32[i][k]
    float wsum = 0.f;
    const float* Ab = A + (size_t)(i0 + 16 * w + 4 * lg) * NK + lm;
#pragma unroll
    for (int r = 0; r < 4; ++r) {
        const float* ar = Ab + (size_t)r * NK;
        wsum += D0[r] * ar[0];
        wsum += D1[r] * ar[16];
        wsum += D2[r] * ar[32];
        wsum += D3[r] * ar[48];
    }
#pragma unroll
    for (int m = 1; m < 64; m <<= 1) wsum += __shfl_xor(wsum, m);
    if (l == 0) red[w] = wsum;
    __syncthreads();

    if (tid == 0) within_part[bid] = red[0] + red[1] + red[2] + red[3];
    for (int c = tid; c < JRANGE; c += 256) {
        float s = csum[0][c] + csum[1][c] + csum[2][c] + csum[3][c];
        atomicAdd(&colsum[j0 + c], s);
    }
}

// ---------- spatial pass 1: argmax ids + counts + coord sums ----------
__global__ __launch_bounds__(256) void spatial1(
    const float* __restrict__ A, const float* __restrict__ pos,
    int* __restrict__ ids, float* __restrict__ counts, float* __restrict__ sums)
{
    int wv = threadIdx.x >> 6, l = threadIdx.x & 63;
    int node = blockIdx.x * 4 + wv;
    float v = A[(size_t)node * NK + l];
    int idx = l;
#pragma unroll
    for (int m = 1; m < 64; m <<= 1) {
        float ov = __shfl_xor(v, m);
        int oi = __shfl_xor(idx, m);
        if (ov > v || (ov == v && oi < idx)) { v = ov; idx = oi; }
    }
    if (l == 0) {
        ids[node] = idx;
        atomicAdd(&counts[idx], 1.0f);
        atomicAdd(&sums[idx * 2 + 0], pos[(size_t)node * 2 + 0]);
        atomicAdd(&sums[idx * 2 + 1], pos[(size_t)node * 2 + 1]);
    }
}

// ---------- spatial pass 2: distances to centroids ----------
__global__ __launch_bounds__(256) void spatial2(
    const int* __restrict__ ids, const float* __restrict__ pos,
    const float* __restrict__ counts, const float* __restrict__ sums,
    float* __restrict__ distsum, int* __restrict__ maxid)
{
    __shared__ float ds[64];
    __shared__ int mx;
    int tid = threadIdx.x;
    if (tid < 64) ds[tid] = 0.f;
    if (tid == 0) mx = 0;
    __syncthreads();
    int i = blockIdx.x * 256 + tid;
    int id = ids[i];
    float den = counts[id] + EPSF;
    float cx = sums[id * 2 + 0] / den;
    float cy = sums[id * 2 + 1] / den;
    float dx = pos[(size_t)i * 2 + 0] - cx;
    float dy = pos[(size_t)i * 2 + 1] - cy;
    atomicAdd(&ds[id], sqrtf(dx * dx + dy * dy));
    atomicMax(&mx, id);
    __syncthreads();
    if (tid < 64) atomicAdd(&distsum[tid], ds[tid]);
    if (tid == 0) atomicMax(maxid, mx);
}

// ---------- finalize ----------
__global__ __launch_bounds__(256) void finalize(
    const float* __restrict__ rowsum, const float* __restrict__ colsum,
    const float* __restrict__ cons, const float* __restrict__ gen,
    const float* __restrict__ within_part, const float* __restrict__ counts,
    const float* __restrict__ distsum, const int* __restrict__ maxid,
    float* __restrict__ out)
{
    __shared__ float redb[4], rede[4], redw[4];
    int tid = threadIdx.x;
    int w = tid >> 6, l = tid & 63;
    float bacc = 0.f, eacc = 0.f, wacc = 0.f;
    for (int i = tid; i < NN; i += 256) {
        float imb = (cons[i] - gen[i]) - (colsum[i] - rowsum[i]);
        bacc += imb * imb;
        eacc += rowsum[i];
    }
    for (int i = tid; i < 1024; i += 256) wacc += within_part[i];
#pragma unroll
    for (int m = 1; m < 64; m <<= 1) {
        bacc += __shfl_xor(bacc, m);
        eacc += __shfl_xor(eacc, m);
        wacc += __shfl_xor(wacc, m);
    }
    if (l == 0) { redb[w] = bacc; rede[w] = eacc; redw[w] = wacc; }
    __syncthreads();

    float sacc = 0.f;
    if (tid < 64) {
        float c = counts[tid];
        float avg = distsum[tid] / (c + EPSF);
        sacc = (c >= 2.0f) ? avg : 0.f;
#pragma unroll
        for (int m = 1; m < 64; m <<= 1) sacc += __shfl_xor(sacc, m);
    }
    if (tid == 0) {
        float balance = (redb[0] + redb[1] + redb[2] + redb[3]) / (float)NN;
        float sumE = rede[0] + rede[1] + rede[2] + rede[3];
        float W = redw[0] + redw[1] + redw[2] + redw[3];
        float clustering = (sumE - 2.0f * W) / ((float)NN * (float)NN + EPSF);
        float nc = (float)(maxid[0] + 1) + EPSF;
        float spatial = sacc / nc;
        float total = 1.0f * balance + 0.5f * spatial + 0.3f * clustering;
        out[0] = total;
        out[1] = balance;
        out[2] = spatial;
        out[3] = clustering;
    }
}

extern "C" void kernel_launch(void* const* d_in, const int* in_sizes, int n_in,
                              void* d_out, int out_size, void* d_ws, size_t ws_size,
                              hipStream_t stream) {
    const float* E    = (const float*)d_in[0];
    const float* A    = (const float*)d_in[1];
    const float* pos  = (const float*)d_in[2];
    const float* cons = (const float*)d_in[3];
    const float* gen  = (const float*)d_in[4];
    float* out = (float*)d_out;

    char* ws = (char*)d_ws;
    unsigned short* AT = (unsigned short*)ws;                 // 64*N bf16 = 1 MB
    float* rowsum      = (float*)(ws + (size_t)2 * NK * NN);  // [N]
    float* colsum      = rowsum + NN;                         // [N]
    float* counts      = colsum + NN;                         // [64]
    float* sums        = counts + 64;                         // [64][2]
    float* distsum     = sums + 128;                          // [64]
    int*   maxid       = (int*)(distsum + 64);                // [1]
    float* within_part = (float*)(maxid + 1);                 // [1024]
    int*   ids         = (int*)(within_part + 1024);          // [N]

    size_t zbytes = ((size_t)NN * 2 + 64 + 128 + 64 + 1) * 4;
    hipMemsetAsync(rowsum, 0, zbytes, stream);

    cvt_at  <<<NN * 16 / 256, 256, 0, stream>>>(A, AT);
    pass_e  <<<(NN / 64) * JSPLIT, 256, 0, stream>>>(E, A, AT, rowsum, colsum, within_part);
    spatial1<<<NN / 4, 256, 0, stream>>>(A, pos, ids, counts, sums);
    spatial2<<<NN / 256, 256, 0, stream>>>(ids, pos, counts, sums, distsum, maxid);
    finalize<<<1, 256, 0, stream>>>(rowsum, colsum, cons, gen, within_part, counts, distsum, maxid, out);
}